// Round 2
// baseline (407.829 us; speedup 1.0000x reference)
//
#include <hip/hip_runtime.h>

typedef __bf16  bf16x8  __attribute__((ext_vector_type(8)));
typedef float   floatx4 __attribute__((ext_vector_type(4)));

constexpr int    GROUPS        = 64;
constexpr int    NDIM          = 32;
constexpr int    BTOT          = 16384;
constexpr int    ROWSTRIDE     = GROUPS * NDIM;   // 2048 floats per batch row
constexpr int    ROWS_PER_BLK  = 256;             // 4 waves * 4 tiles * 16 rows
constexpr int    UT_STRIDE     = 40;              // bf16 elems, padded (16B-aligned rows)
constexpr int    T_STRIDE      = 36;              // fp32 elems, padded
constexpr size_t HT_OFF        = (size_t)BTOT * ROWSTRIDE;

__device__ __forceinline__ float fast_sigmoid(float x) {
    return 1.0f / (1.0f + __expf(-x));
}
// tanh(x) = 1 - 2/(exp(2x)+1): saturates correctly at +/-inf, no NaN for finite x.
__device__ __forceinline__ float fast_tanh(float x) {
    float e = __expf(2.0f * x);
    return 1.0f - 2.0f / (e + 1.0f);
}

__global__ __launch_bounds__(256, 4)
void gru_ode_kernel(const float* __restrict__ hin,
                    const float* __restrict__ Ur,
                    const float* __restrict__ Uz,
                    const float* __restrict__ Uh,
                    const float* __restrict__ br,
                    const float* __restrict__ bz,
                    const float* __restrict__ bh,
                    float*       __restrict__ out)
{
    // U^T tiles [n][k] (bf16) so B-fragments are contiguous ds_read_b128.
    __shared__ alignas(16) __bf16 sUT[3][32 * UT_STRIDE];   // 7680 B
    // Per-wave private fp32 tiles for the C-layout <-> A-layout round trips.
    __shared__ alignas(16) float sH[4][16 * T_STRIDE];      // 9216 B
    __shared__ alignas(16) float sR[4][16 * T_STRIDE];      // 9216 B

    const int tid = threadIdx.x;
    const int g   = blockIdx.x & (GROUPS - 1);
    const int rb  = blockIdx.x >> 6;

    // ---- stage U_r/U_z/U_h[g] transposed + bf16-cast into LDS (once per block) ----
    {
        const int k  = tid >> 3;            // 0..31  (contraction index j of einsum)
        const int n0 = (tid & 7) * 4;       // 0,4,...,28 (output index)
        const float* srcs[3] = { Ur + g * 1024, Uz + g * 1024, Uh + g * 1024 };
        #pragma unroll
        for (int m = 0; m < 3; ++m) {
            const floatx4 u4 = *(const floatx4*)(srcs[m] + k * 32 + n0);
            #pragma unroll
            for (int j = 0; j < 4; ++j)
                sUT[m][(n0 + j) * UT_STRIDE + k] = (__bf16)u4[j];
        }
    }
    __syncthreads();

    const int lane = tid & 63;
    const int wave = tid >> 6;
    const int col  = lane & 15;     // C-layout col / A-layout row / B-layout n
    const int quad = lane >> 4;     // 0..3
    const int kq   = quad * 8;      // A/B-layout k base

    // B-fragments: lane holds B[k=quad*8+j][n] = UT[n][kq..kq+7]
    const bf16x8 fr0 = *(const bf16x8*)&sUT[0][ col       * UT_STRIDE + kq];
    const bf16x8 fr1 = *(const bf16x8*)&sUT[0][(col + 16) * UT_STRIDE + kq];
    const bf16x8 fz0 = *(const bf16x8*)&sUT[1][ col       * UT_STRIDE + kq];
    const bf16x8 fz1 = *(const bf16x8*)&sUT[1][(col + 16) * UT_STRIDE + kq];
    const bf16x8 fh0 = *(const bf16x8*)&sUT[2][ col       * UT_STRIDE + kq];
    const bf16x8 fh1 = *(const bf16x8*)&sUT[2][(col + 16) * UT_STRIDE + kq];

    const float bR0 = br[g * 32 + col], bR1 = br[g * 32 + col + 16];
    const float bZ0 = bz[g * 32 + col], bZ1 = bz[g * 32 + col + 16];
    const float bH0 = bh[g * 32 + col], bH1 = bh[g * 32 + col + 16];

    float* myH = sH[wave];
    float* myR = sR[wave];
    const int rowA    = col;                              // A-layout row
    const int baseRow = rb * ROWS_PER_BLK + wave * 64;
    const floatx4 zero4 = {0.f, 0.f, 0.f, 0.f};

    for (int tt = 0; tt < 4; ++tt) {
        const int r0 = baseRow + tt * 16;

        // A-fragment of h from global (f32): 32 B/lane; every 64 B line fully used.
        const float* hp = hin + (size_t)(r0 + rowA) * ROWSTRIDE + g * NDIM + kq;
        const floatx4 h0 = *(const floatx4*)hp;
        const floatx4 h1 = *(const floatx4*)(hp + 4);

        bf16x8 ah;
        #pragma unroll
        for (int j = 0; j < 4; ++j) {
            ah[j]     = (__bf16)h0[j];
            ah[j + 4] = (__bf16)h1[j];
        }

        // stash exact f32 h (A-positions) for later C-layout readback
        *(floatx4*)&myH[rowA * T_STRIDE + kq]     = h0;
        *(floatx4*)&myH[rowA * T_STRIDE + kq + 4] = h1;

        floatx4 ar0 = __builtin_amdgcn_mfma_f32_16x16x32_bf16(ah, fr0, zero4, 0, 0, 0);
        floatx4 ar1 = __builtin_amdgcn_mfma_f32_16x16x32_bf16(ah, fr1, zero4, 0, 0, 0);
        floatx4 az0 = __builtin_amdgcn_mfma_f32_16x16x32_bf16(ah, fz0, zero4, 0, 0, 0);
        floatx4 az1 = __builtin_amdgcn_mfma_f32_16x16x32_bf16(ah, fz1, zero4, 0, 0, 0);

        // r,z: C/D layout col=lane&15, row=quad*4+reg
        float z0v[4], z1v[4];
        #pragma unroll
        for (int j = 0; j < 4; ++j) {
            float rv0 = fast_sigmoid(ar0[j] + bR0);
            float rv1 = fast_sigmoid(ar1[j] + bR1);
            z0v[j] = fast_sigmoid(az0[j] + bZ0);
            z1v[j] = fast_sigmoid(az1[j] + bZ1);
            myR[(quad * 4 + j) * T_STRIDE + col]      = rv0;
            myR[(quad * 4 + j) * T_STRIDE + col + 16] = rv1;
        }

        // drain LDS writes; wave-private round trip (no cross-wave data).
        // sched_barrier pins compiler ordering; waitcnt 0xC07F = lgkmcnt(0) only.
        __builtin_amdgcn_sched_barrier(0);
        __builtin_amdgcn_s_waitcnt(0xC07F);
        __builtin_amdgcn_sched_barrier(0);

        // read r back at A-layout positions, fuse r*h, cast to bf16
        floatx4 ra  = *(const floatx4*)&myR[rowA * T_STRIDE + kq];
        floatx4 rb4 = *(const floatx4*)&myR[rowA * T_STRIDE + kq + 4];
        bf16x8 arh;
        #pragma unroll
        for (int j = 0; j < 4; ++j) {
            arh[j]     = (__bf16)(ra[j]  * h0[j]);
            arh[j + 4] = (__bf16)(rb4[j] * h1[j]);
        }

        floatx4 ahh0 = __builtin_amdgcn_mfma_f32_16x16x32_bf16(arh, fh0, zero4, 0, 0, 0);
        floatx4 ahh1 = __builtin_amdgcn_mfma_f32_16x16x32_bf16(arh, fh1, zero4, 0, 0, 0);

        // epilogue: tanh, dh=(1-z)(h~-h); h fetched at C-positions from LDS
        #pragma unroll
        for (int j = 0; j < 4; ++j) {
            const int row = quad * 4 + j;
            float ht0 = fast_tanh(ahh0[j] + bH0);
            float ht1 = fast_tanh(ahh1[j] + bH1);
            float hc0 = myH[row * T_STRIDE + col];
            float hc1 = myH[row * T_STRIDE + col + 16];
            float dh0 = (1.0f - z0v[j]) * (ht0 - hc0);
            float dh1 = (1.0f - z1v[j]) * (ht1 - hc1);
            size_t ob = (size_t)(r0 + row) * ROWSTRIDE + g * NDIM;
            out[ob + col]               = dh0;
            out[ob + col + 16]          = dh1;
            out[HT_OFF + ob + col]      = ht0;
            out[HT_OFF + ob + col + 16] = ht1;
        }
    }
}

extern "C" void kernel_launch(void* const* d_in, const int* in_sizes, int n_in,
                              void* d_out, int out_size, void* d_ws, size_t ws_size,
                              hipStream_t stream) {
    // d_in[0] = t (int scalar, unused by the math)
    const float* hin = (const float*)d_in[1];
    const float* Ur  = (const float*)d_in[2];
    const float* Uz  = (const float*)d_in[3];
    const float* Uh  = (const float*)d_in[4];
    const float* br  = (const float*)d_in[5];
    const float* bz  = (const float*)d_in[6];
    const float* bh  = (const float*)d_in[7];
    float* out = (float*)d_out;

    dim3 grid(GROUPS * (BTOT / ROWS_PER_BLK));   // 64 * 64 = 4096 blocks
    gru_ode_kernel<<<grid, 256, 0, stream>>>(hin, Ur, Uz, Uh, br, bz, bh, out);
}

// Round 3
// 404.727 us; speedup vs baseline: 1.0077x; 1.0077x over previous
//
#include <hip/hip_runtime.h>

typedef __bf16  bf16x8  __attribute__((ext_vector_type(8)));
typedef float   floatx4 __attribute__((ext_vector_type(4)));

constexpr int    GROUPS        = 64;
constexpr int    NDIM          = 32;
constexpr int    BTOT          = 16384;
constexpr int    ROWSTRIDE     = GROUPS * NDIM;   // 2048 floats per batch row
constexpr int    ROWS_PER_BLK  = 256;             // 4 waves * 4 tiles * 16 rows
constexpr int    UT_STRIDE     = 40;              // bf16 elems, padded (16B-aligned rows)
constexpr int    T_STRIDE      = 36;              // fp32 elems, padded
constexpr size_t HT_OFF        = (size_t)BTOT * ROWSTRIDE;

// v_rcp_f32: ~1 ULP, no IEEE div sequence, no VCC serialization.
__device__ __forceinline__ float fast_rcp(float x) { return __builtin_amdgcn_rcpf(x); }
__device__ __forceinline__ float fast_sigmoid(float x) {
    return fast_rcp(1.0f + __expf(-x));
}
// tanh(x) = 1 - 2/(exp(2x)+1): saturates correctly, no NaN for finite x.
__device__ __forceinline__ float fast_tanh(float x) {
    return 1.0f - 2.0f * fast_rcp(__expf(2.0f * x) + 1.0f);
}

__global__ __launch_bounds__(256, 2)   // cap 256 VGPR: no spills; allocator free to use fewer
void gru_ode_kernel(const float* __restrict__ hin,
                    const float* __restrict__ Ur,
                    const float* __restrict__ Uz,
                    const float* __restrict__ Uh,
                    const float* __restrict__ br,
                    const float* __restrict__ bz,
                    const float* __restrict__ bh,
                    float*       __restrict__ out)
{
    // U^T tiles [n][k] (bf16) so B-fragments are contiguous ds_read_b128.
    __shared__ alignas(16) __bf16 sUT[3][32 * UT_STRIDE];   // 7680 B
    // Per-wave private fp32 tiles for the C-layout <-> A-layout round trips.
    __shared__ alignas(16) float sH[4][16 * T_STRIDE];      // 9216 B
    __shared__ alignas(16) float sR[4][16 * T_STRIDE];      // 9216 B

    const int tid = threadIdx.x;
    const int g   = blockIdx.x & (GROUPS - 1);
    const int rb  = blockIdx.x >> 6;

    // ---- stage U_r/U_z/U_h[g] transposed + bf16-cast into LDS (once per block) ----
    {
        const int k  = tid >> 3;            // 0..31  (contraction index j of einsum)
        const int n0 = (tid & 7) * 4;       // 0,4,...,28 (output index)
        const float* srcs[3] = { Ur + g * 1024, Uz + g * 1024, Uh + g * 1024 };
        #pragma unroll
        for (int m = 0; m < 3; ++m) {
            const floatx4 u4 = *(const floatx4*)(srcs[m] + k * 32 + n0);
            #pragma unroll
            for (int j = 0; j < 4; ++j)
                sUT[m][(n0 + j) * UT_STRIDE + k] = (__bf16)u4[j];
        }
    }
    __syncthreads();

    const int lane = tid & 63;
    const int wave = tid >> 6;
    const int col  = lane & 15;     // C-layout col / A-layout row / B-layout n
    const int quad = lane >> 4;     // 0..3
    const int kq   = quad * 8;      // A/B-layout k base

    // B-fragments: lane holds B[k=quad*8+j][n] = UT[n][kq..kq+7]
    const bf16x8 fr0 = *(const bf16x8*)&sUT[0][ col       * UT_STRIDE + kq];
    const bf16x8 fr1 = *(const bf16x8*)&sUT[0][(col + 16) * UT_STRIDE + kq];
    const bf16x8 fz0 = *(const bf16x8*)&sUT[1][ col       * UT_STRIDE + kq];
    const bf16x8 fz1 = *(const bf16x8*)&sUT[1][(col + 16) * UT_STRIDE + kq];
    const bf16x8 fh0 = *(const bf16x8*)&sUT[2][ col       * UT_STRIDE + kq];
    const bf16x8 fh1 = *(const bf16x8*)&sUT[2][(col + 16) * UT_STRIDE + kq];

    const float bR0 = br[g * 32 + col], bR1 = br[g * 32 + col + 16];
    const float bZ0 = bz[g * 32 + col], bZ1 = bz[g * 32 + col + 16];
    const float bH0 = bh[g * 32 + col], bH1 = bh[g * 32 + col + 16];

    float* myH = sH[wave];
    float* myR = sR[wave];
    const int rowA    = col;                              // A-layout row
    const int baseRow = rb * ROWS_PER_BLK + wave * 64;
    const floatx4 zero4 = {0.f, 0.f, 0.f, 0.f};

    // Precomputed streaming pointers (advance by 16 rows per tile).
    const float* hp  = hin + (size_t)(baseRow + rowA) * ROWSTRIDE + g * NDIM + kq;
    float*       op  = out + (size_t)(baseRow + quad * 4) * ROWSTRIDE + g * NDIM + col;

    for (int tt = 0; tt < 4; ++tt) {
        // A-fragment of h from global (f32): 32 B/lane.
        const floatx4 h0 = *(const floatx4*)hp;
        const floatx4 h1 = *(const floatx4*)(hp + 4);
        hp += 16 * ROWSTRIDE;

        bf16x8 ah;
        #pragma unroll
        for (int j = 0; j < 4; ++j) {
            ah[j]     = (__bf16)h0[j];
            ah[j + 4] = (__bf16)h1[j];
        }

        // stash exact f32 h (A-positions) for later C-layout readback
        *(floatx4*)&myH[rowA * T_STRIDE + kq]     = h0;
        *(floatx4*)&myH[rowA * T_STRIDE + kq + 4] = h1;

        floatx4 ar0 = __builtin_amdgcn_mfma_f32_16x16x32_bf16(ah, fr0, zero4, 0, 0, 0);
        floatx4 ar1 = __builtin_amdgcn_mfma_f32_16x16x32_bf16(ah, fr1, zero4, 0, 0, 0);
        floatx4 az0 = __builtin_amdgcn_mfma_f32_16x16x32_bf16(ah, fz0, zero4, 0, 0, 0);
        floatx4 az1 = __builtin_amdgcn_mfma_f32_16x16x32_bf16(ah, fz1, zero4, 0, 0, 0);

        // r: C/D layout col=lane&15, row=quad*4+reg
        #pragma unroll
        for (int j = 0; j < 4; ++j) {
            float rv0 = fast_sigmoid(ar0[j] + bR0);
            float rv1 = fast_sigmoid(ar1[j] + bR1);
            myR[(quad * 4 + j) * T_STRIDE + col]      = rv0;
            myR[(quad * 4 + j) * T_STRIDE + col + 16] = rv1;
        }

        // drain LDS writes; wave-private round trip (no cross-wave data).
        // sched_barrier pins compiler ordering; waitcnt 0xC07F = lgkmcnt(0) only.
        __builtin_amdgcn_sched_barrier(0);
        __builtin_amdgcn_s_waitcnt(0xC07F);
        __builtin_amdgcn_sched_barrier(0);

        // read r back at A-layout positions, fuse r*h, cast to bf16
        floatx4 ra  = *(const floatx4*)&myR[rowA * T_STRIDE + kq];
        floatx4 rb4 = *(const floatx4*)&myR[rowA * T_STRIDE + kq + 4];
        bf16x8 arh;
        #pragma unroll
        for (int j = 0; j < 4; ++j) {
            arh[j]     = (__bf16)(ra[j]  * h0[j]);
            arh[j + 4] = (__bf16)(rb4[j] * h1[j]);
        }

        floatx4 ahh0 = __builtin_amdgcn_mfma_f32_16x16x32_bf16(arh, fh0, zero4, 0, 0, 0);
        floatx4 ahh1 = __builtin_amdgcn_mfma_f32_16x16x32_bf16(arh, fh1, zero4, 0, 0, 0);

        // epilogue: z, tanh, dh=(1-z)(h~-h); h fetched at C-positions from LDS
        #pragma unroll
        for (int j = 0; j < 4; ++j) {
            const int row = quad * 4 + j;
            float z0  = fast_sigmoid(az0[j] + bZ0);
            float z1  = fast_sigmoid(az1[j] + bZ1);
            float ht0 = fast_tanh(ahh0[j] + bH0);
            float ht1 = fast_tanh(ahh1[j] + bH1);
            float hc0 = myH[row * T_STRIDE + col];
            float hc1 = myH[row * T_STRIDE + col + 16];
            float dh0 = (1.0f - z0) * (ht0 - hc0);
            float dh1 = (1.0f - z1) * (ht1 - hc1);
            float* o  = op + j * ROWSTRIDE;
            o[0]            = dh0;
            o[16]           = dh1;
            o[HT_OFF]       = ht0;
            o[HT_OFF + 16]  = ht1;
        }
        op += 16 * ROWSTRIDE;
    }
}

extern "C" void kernel_launch(void* const* d_in, const int* in_sizes, int n_in,
                              void* d_out, int out_size, void* d_ws, size_t ws_size,
                              hipStream_t stream) {
    // d_in[0] = t (int scalar, unused by the math)
    const float* hin = (const float*)d_in[1];
    const float* Ur  = (const float*)d_in[2];
    const float* Uz  = (const float*)d_in[3];
    const float* Uh  = (const float*)d_in[4];
    const float* br  = (const float*)d_in[5];
    const float* bz  = (const float*)d_in[6];
    const float* bh  = (const float*)d_in[7];
    float* out = (float*)d_out;

    dim3 grid(GROUPS * (BTOT / ROWS_PER_BLK));   // 64 * 64 = 4096 blocks
    gru_ode_kernel<<<grid, 256, 0, stream>>>(hin, Ur, Uz, Uh, br, bz, bh, out);
}